// Round 1
// baseline (11437.093 us; speedup 1.0000x reference)
//
#include <hip/hip_runtime.h>

#define Bn 8
#define Tn 2048
#define Hn 2048
#define Cn 16
#define NCn (Tn / Cn)    // 128 chunks
#define M2n (NCn * Bn)   // 1024 scan rows
#define TS 64
#define KT 16

// ---------------------------------------------------------------------------
// K0: canonicalize reset input (format-probe int32 / float32 / bytes),
//     compute per-(chunk,row) first-reset position, cut flag, anyUncut flag.
// ---------------------------------------------------------------------------
__global__ __launch_bounds__(256) void k_reset_prep(const unsigned int* __restrict__ rin,
                                                    unsigned char* __restrict__ r8,
                                                    int* __restrict__ cut,
                                                    int* __restrict__ firstReset,
                                                    int* __restrict__ anyUncut) {
    __shared__ int s_badInt, s_badFloat;
    if (threadIdx.x == 0) { s_badInt = 0; s_badFloat = 0; }
    __syncthreads();
    int badI = 0, badF = 0;
    // 4096 words = whole buffer if bytes, first quarter if int32 — safe either way.
    for (int i = threadIdx.x; i < 4096; i += 256) {
        unsigned int v = rin[i];
        if (v > 1u) badI = 1;
        if (v != 0u && v != 0x3f800000u) badF = 1;
    }
    if (badI) atomicOr(&s_badInt, 1);
    if (badF) atomicOr(&s_badFloat, 1);
    __syncthreads();
    const int fmt = (!s_badInt) ? 0 : ((!s_badFloat) ? 1 : 2);  // 0:int32 1:f32 2:bytes
    const unsigned char* rb = (const unsigned char*)rin;
    const float* rf = (const float*)rin;
    for (int i = threadIdx.x; i < Bn * Tn; i += 256) {
        unsigned char v;
        if (fmt == 0)      v = (unsigned char)(rin[i] != 0u);
        else if (fmt == 1) v = (unsigned char)(rf[i] != 0.0f);
        else               v = (unsigned char)(rb[i] != 0);
        r8[i] = v;
    }
    __syncthreads();
    if (threadIdx.x == 0) *anyUncut = 0;
    __syncthreads();
    int anyU = 0;
    for (int m = threadIdx.x; m < NCn * Bn; m += 256) {
        int c = m / Bn, b = m % Bn;
        int fr = Cn;
        for (int j = 0; j < Cn; j++) {
            if (r8[b * Tn + c * Cn + j]) { fr = j; break; }
        }
        firstReset[m] = fr;
        int ct = (fr < Cn);
        cut[m] = ct;
        if (!ct && c < NCn - 1) anyU = 1;
    }
    if (anyU) atomicOr(anyUncut, 1);
}

// ---------------------------------------------------------------------------
// K1: bx = x @ Bmat  (NN GEMM, M=B*T, N=K=H). Writes into d_out.
// ---------------------------------------------------------------------------
__global__ __launch_bounds__(256) void k_gemm_bx(const float* __restrict__ X,
                                                 const float* __restrict__ Bm,
                                                 float* __restrict__ Out) {
    __shared__ float As[KT][TS + 1];
    __shared__ float Bs[KT][TS + 1];
    const int tid = threadIdx.x, tx = tid & 15, ty = tid >> 4;
    const int m0 = blockIdx.y * TS, n0 = blockIdx.x * TS;
    float acc[4][4] = {};
    for (int k0 = 0; k0 < Hn; k0 += KT) {
        for (int i = tid; i < TS * KT; i += 256) {
            int r = i / KT, c = i % KT;
            As[c][r] = X[(size_t)(m0 + r) * Hn + k0 + c];
        }
        for (int i = tid; i < TS * KT; i += 256) {
            int c = i / TS, n = i % TS;
            Bs[c][n] = Bm[(size_t)(k0 + c) * Hn + n0 + n];
        }
        __syncthreads();
#pragma unroll
        for (int kk = 0; kk < KT; kk++) {
            float a[4], b[4];
#pragma unroll
            for (int i = 0; i < 4; i++) a[i] = As[kk][ty * 4 + i];
#pragma unroll
            for (int i = 0; i < 4; i++) b[i] = Bs[kk][tx * 4 + i];
#pragma unroll
            for (int i = 0; i < 4; i++)
#pragma unroll
                for (int jj = 0; jj < 4; jj++) acc[i][jj] += a[i] * b[jj];
        }
        __syncthreads();
    }
#pragma unroll
    for (int i = 0; i < 4; i++) {
        size_t row = (size_t)(m0 + ty * 4 + i) * Hn + n0 + tx * 4;
#pragma unroll
        for (int jj = 0; jj < 4; jj++) Out[row + jj] = acc[i][jj];
    }
}

// ---------------------------------------------------------------------------
// K2: one chunk-local scan step j (all chunks in parallel).
//     Snew[m,:] = (reset ? 0 : Sprev[m,:] @ A^T) + bx[b,t,:]; writeback to Out.
// ---------------------------------------------------------------------------
__global__ __launch_bounds__(256) void k_scan_step(const float* __restrict__ Sp,
                                                   float* __restrict__ Sn,
                                                   const float* __restrict__ A,
                                                   float* __restrict__ Out,
                                                   const unsigned char* __restrict__ r8,
                                                   int j) {
    __shared__ float As[KT][TS + 1];   // Sp fragment [kk][mm]
    __shared__ float Bs[TS][KT + 1];   // A fragment [nn][kk]
    const int tid = threadIdx.x, tx = tid & 15, ty = tid >> 4;
    const int m0 = blockIdx.y * TS, n0 = blockIdx.x * TS;
    float acc[4][4] = {};
    for (int k0 = 0; k0 < Hn; k0 += KT) {
        for (int i = tid; i < TS * KT; i += 256) {
            int r = i / KT, c = i % KT;
            As[c][r] = Sp[(size_t)(m0 + r) * Hn + k0 + c];
        }
        for (int i = tid; i < TS * KT; i += 256) {
            int r = i / KT, c = i % KT;
            Bs[r][c] = A[(size_t)(n0 + r) * Hn + k0 + c];
        }
        __syncthreads();
#pragma unroll
        for (int kk = 0; kk < KT; kk++) {
            float a[4], b[4];
#pragma unroll
            for (int i = 0; i < 4; i++) a[i] = As[kk][ty * 4 + i];
#pragma unroll
            for (int i = 0; i < 4; i++) b[i] = Bs[tx * 4 + i][kk];
#pragma unroll
            for (int i = 0; i < 4; i++)
#pragma unroll
                for (int jj = 0; jj < 4; jj++) acc[i][jj] += a[i] * b[jj];
        }
        __syncthreads();
    }
#pragma unroll
    for (int i = 0; i < 4; i++) {
        int m = m0 + ty * 4 + i;
        int c = m / Bn, b = m & (Bn - 1);
        int t = c * Cn + j;
        int rfl = r8[b * Tn + t];
        size_t ob = ((size_t)b * Tn + t) * Hn + n0 + tx * 4;
        size_t sb = (size_t)m * Hn + n0 + tx * 4;
#pragma unroll
        for (int jj = 0; jj < 4; jj++) {
            float v = (rfl ? 0.0f : acc[i][jj]) + Out[ob + jj];
            Out[ob + jj] = v;
            Sn[sb + jj] = v;
        }
    }
}

// ---------------------------------------------------------------------------
// K3a: h_in[c] = local_end[c-1] (exact when chunk c-1 contains a reset; the
//      rare uncut case gets the A^C term added by k_fallback).
// ---------------------------------------------------------------------------
__global__ __launch_bounds__(256) void k_hin(const float* __restrict__ Out,
                                             float* __restrict__ Hin) {
    size_t i = (size_t)blockIdx.x * 256 + threadIdx.x;  // over M2n*Hn
    int m = (int)(i / Hn);
    int n = (int)(i & (Hn - 1));
    int c = m / Bn, b = m & (Bn - 1);
    Hin[i] = (c == 0) ? 0.0f : Out[((size_t)b * Tn + (size_t)c * Cn - 1) * Hn + n];
}

// ---------------------------------------------------------------------------
// K3b: exact fallback for chunks with no reset (prob ~2^-16 per row-chunk).
//      Single block, sequential over chunks; instant no-op when not needed.
// ---------------------------------------------------------------------------
__global__ __launch_bounds__(1024) void k_fallback(float* __restrict__ Hin,
                                                   const float* __restrict__ A,
                                                   const int* __restrict__ cut,
                                                   const int* __restrict__ anyUncut) {
    if (*anyUncut == 0) return;
    __shared__ float v0[Hn];
    __shared__ float v1[Hn];
    for (int c = 1; c < NCn; c++) {
        for (int b = 0; b < Bn; b++) {
            if (cut[(c - 1) * Bn + b]) continue;
            for (int n = threadIdx.x; n < Hn; n += 1024)
                v0[n] = Hin[((size_t)(c - 1) * Bn + b) * Hn + n];
            __syncthreads();
            for (int s = 0; s < Cn; s++) {
                float* pin = (s & 1) ? v1 : v0;
                float* pout = (s & 1) ? v0 : v1;
                for (int n = threadIdx.x; n < Hn; n += 1024) {
                    float accv = 0.0f;
                    const float* Ar = &A[(size_t)n * Hn];
                    for (int k = 0; k < Hn; k++) accv += pin[k] * Ar[k];
                    pout[n] = accv;
                }
                __syncthreads();
            }
            float* pres = (Cn & 1) ? v1 : v0;
            for (int n = threadIdx.x; n < Hn; n += 1024)
                Hin[((size_t)c * Bn + b) * Hn + n] += pres[n];
            __syncthreads();
        }
    }
}

// ---------------------------------------------------------------------------
// K4: correction step j: u <- u @ A^T, kill rows whose chunk has seen a reset,
//     Out[b, c*C+j, :] += u. Early-out for all-dead blocks.
// ---------------------------------------------------------------------------
__global__ __launch_bounds__(256) void k_corr_step(const float* __restrict__ Up,
                                                   float* __restrict__ Un,
                                                   const float* __restrict__ A,
                                                   float* __restrict__ Out,
                                                   const int* __restrict__ firstReset,
                                                   int j) {
    __shared__ float As[KT][TS + 1];
    __shared__ float Bs[TS][KT + 1];
    __shared__ int smax;
    const int tid = threadIdx.x, tx = tid & 15, ty = tid >> 4;
    const int m0 = blockIdx.y * TS, n0 = blockIdx.x * TS;
    if (tid == 0) smax = 0;
    __syncthreads();
    if (tid < TS) atomicMax(&smax, firstReset[m0 + tid]);
    __syncthreads();
    const int maxFR = smax;
    if (j >= maxFR + 2) return;        // both u buffers already zero for this tile
    if (j >= maxFR) {                  // all rows dead: just zero the output tile
#pragma unroll
        for (int i = 0; i < 4; i++) {
            int m = m0 + ty * 4 + i;
            size_t sb = (size_t)m * Hn + n0 + tx * 4;
#pragma unroll
            for (int jj = 0; jj < 4; jj++) Un[sb + jj] = 0.0f;
        }
        return;
    }
    float acc[4][4] = {};
    for (int k0 = 0; k0 < Hn; k0 += KT) {
        for (int i = tid; i < TS * KT; i += 256) {
            int r = i / KT, c = i % KT;
            As[c][r] = Up[(size_t)(m0 + r) * Hn + k0 + c];
        }
        for (int i = tid; i < TS * KT; i += 256) {
            int r = i / KT, c = i % KT;
            Bs[r][c] = A[(size_t)(n0 + r) * Hn + k0 + c];
        }
        __syncthreads();
#pragma unroll
        for (int kk = 0; kk < KT; kk++) {
            float a[4], b[4];
#pragma unroll
            for (int i = 0; i < 4; i++) a[i] = As[kk][ty * 4 + i];
#pragma unroll
            for (int i = 0; i < 4; i++) b[i] = Bs[tx * 4 + i][kk];
#pragma unroll
            for (int i = 0; i < 4; i++)
#pragma unroll
                for (int jj = 0; jj < 4; jj++) acc[i][jj] += a[i] * b[jj];
        }
        __syncthreads();
    }
#pragma unroll
    for (int i = 0; i < 4; i++) {
        int m = m0 + ty * 4 + i;
        int c = m / Bn, b = m & (Bn - 1);
        int t = c * Cn + j;
        int alive = (j < firstReset[m]);
        size_t sb = (size_t)m * Hn + n0 + tx * 4;
        size_t ob = ((size_t)b * Tn + t) * Hn + n0 + tx * 4;
#pragma unroll
        for (int jj = 0; jj < 4; jj++) {
            float v = alive ? acc[i][jj] : 0.0f;
            Un[sb + jj] = v;
            if (alive) Out[ob + jj] += v;
        }
    }
}

extern "C" void kernel_launch(void* const* d_in, const int* in_sizes, int n_in,
                              void* d_out, int out_size, void* d_ws, size_t ws_size,
                              hipStream_t stream) {
    const float* x = (const float*)d_in[0];
    const unsigned int* rst = (const unsigned int*)d_in[1];
    const float* Am = (const float*)d_in[2];
    const float* Bm = (const float*)d_in[3];
    float* Out = (float*)d_out;
    char* ws = (char*)d_ws;

    unsigned char* r8 = (unsigned char*)ws;            // 16 KB
    int* cut = (int*)(ws + 16384);                     // 4 KB
    int* firstReset = (int*)(ws + 16384 + 4096);       // 4 KB
    int* anyUncut = (int*)(ws + 16384 + 8192);         // 4 B
    float* sA = (float*)(ws + (1 << 16));              // 8 MB (state ping / Hin)
    float* sB = sA + (size_t)M2n * Hn;                 // 8 MB (state pong / u)

    k_reset_prep<<<1, 256, 0, stream>>>(rst, r8, cut, firstReset, anyUncut);
    hipMemsetAsync(sA, 0, (size_t)M2n * Hn * sizeof(float), stream);

    // Phase 1: bx into d_out
    k_gemm_bx<<<dim3(Hn / TS, (Bn * Tn) / TS), 256, 0, stream>>>(x, Bm, Out);

    // Phase 2: chunk-local scans (C sequential steps, ping-pong state)
    for (int j = 0; j < Cn; j++) {
        const float* sp = (j & 1) ? sB : sA;
        float* sn = (j & 1) ? sA : sB;
        k_scan_step<<<dim3(Hn / TS, M2n / TS), 256, 0, stream>>>(sp, sn, Am, Out, r8, j);
    }

    // Phase 3: carry-in per chunk (+ exact fallback for uncut chunks)
    k_hin<<<dim3((M2n * Hn) / 256), 256, 0, stream>>>(Out, sA);
    k_fallback<<<1, 1024, 0, stream>>>(sA, Am, cut, anyUncut);

    // Phase 4: corrections (C sequential steps, ping-pong u starting from Hin=sA)
    for (int j = 0; j < Cn; j++) {
        const float* up = (j & 1) ? sB : sA;
        float* un = (j & 1) ? sA : sB;
        k_corr_step<<<dim3(Hn / TS, M2n / TS), 256, 0, stream>>>(up, un, Am, Out, firstReset, j);
    }
}

// Round 2
// 4622.917 us; speedup vs baseline: 2.4740x; 2.4740x over previous
//
#include <hip/hip_runtime.h>

#define Hn 2048
#define Bn 8
#define Tn 2048
#define Cn 16
#define NCn (Tn / Cn)     // 128 chunks
#define M2n (NCn * Bn)    // 1024 scan rows

using f32x4 = __attribute__((ext_vector_type(4))) float;
using u32x4 = __attribute__((ext_vector_type(4))) unsigned int;
using us4   = __attribute__((ext_vector_type(4))) unsigned short;
using bf8   = __attribute__((ext_vector_type(8))) short;
using f4    = __attribute__((ext_vector_type(4))) float;

__device__ __forceinline__ unsigned short f2bf(float f) {
    unsigned u = __builtin_bit_cast(unsigned, f);
    u = u + 0x7fffu + ((u >> 16) & 1u);
    return (unsigned short)(u >> 16);
}
__device__ __forceinline__ float bf2f(unsigned short h) {
    unsigned u = ((unsigned)h) << 16;
    return __builtin_bit_cast(float, u);
}
__device__ __forceinline__ void split3f(float v, unsigned short& a, unsigned short& b, unsigned short& c) {
    a = f2bf(v); float r = v - bf2f(a);
    b = f2bf(r); float r2 = r - bf2f(b);
    c = f2bf(r2);
}

// ---------------------------------------------------------------------------
// K0: canonicalize reset input, firstReset / cut / anyUncut.
// ---------------------------------------------------------------------------
__global__ __launch_bounds__(256) void k_reset_prep(const unsigned int* __restrict__ rin,
                                                    unsigned char* __restrict__ r8,
                                                    int* __restrict__ cut,
                                                    int* __restrict__ firstReset,
                                                    int* __restrict__ anyUncut) {
    __shared__ int s_badInt, s_badFloat;
    if (threadIdx.x == 0) { s_badInt = 0; s_badFloat = 0; }
    __syncthreads();
    int badI = 0, badF = 0;
    for (int i = threadIdx.x; i < 4096; i += 256) {
        unsigned int v = rin[i];
        if (v > 1u) badI = 1;
        if (v != 0u && v != 0x3f800000u) badF = 1;
    }
    if (badI) atomicOr(&s_badInt, 1);
    if (badF) atomicOr(&s_badFloat, 1);
    __syncthreads();
    const int fmt = (!s_badInt) ? 0 : ((!s_badFloat) ? 1 : 2);
    const unsigned char* rb = (const unsigned char*)rin;
    const float* rf = (const float*)rin;
    for (int i = threadIdx.x; i < Bn * Tn; i += 256) {
        unsigned char v;
        if (fmt == 0)      v = (unsigned char)(rin[i] != 0u);
        else if (fmt == 1) v = (unsigned char)(rf[i] != 0.0f);
        else               v = (unsigned char)(rb[i] != 0);
        r8[i] = v;
    }
    __syncthreads();
    if (threadIdx.x == 0) *anyUncut = 0;
    __syncthreads();
    int anyU = 0;
    for (int m = threadIdx.x; m < NCn * Bn; m += 256) {
        int c = m / Bn, b = m % Bn;
        int fr = Cn;
        for (int j = 0; j < Cn; j++) {
            if (r8[b * Tn + c * Cn + j]) { fr = j; break; }
        }
        firstReset[m] = fr;
        int ct = (fr < Cn);
        cut[m] = ct;
        if (!ct && c < NCn - 1) anyU = 1;
    }
    if (anyU) atomicOr(anyUncut, 1);
}

// ---------------------------------------------------------------------------
// Split pre-passes
// ---------------------------------------------------------------------------
__global__ __launch_bounds__(256) void k_split_A3(const float* __restrict__ A,
                                                  unsigned short* __restrict__ a1,
                                                  unsigned short* __restrict__ a2,
                                                  unsigned short* __restrict__ a3) {
    size_t i = ((size_t)blockIdx.x * 256 + threadIdx.x) * 4;
    f32x4 v = *(const f32x4*)&A[i];
    us4 h1, h2, h3;
#pragma unroll
    for (int e = 0; e < 4; e++) {
        unsigned short x1, x2, x3;
        split3f(v[e], x1, x2, x3);
        h1[e] = x1; h2[e] = x2; h3[e] = x3;
    }
    *(us4*)&a1[i] = h1; *(us4*)&a2[i] = h2; *(us4*)&a3[i] = h3;
}

__global__ __launch_bounds__(256) void k_split_Bt(const float* __restrict__ Bm,
                                                  unsigned short* __restrict__ b1,
                                                  unsigned short* __restrict__ b2) {
    __shared__ float tile[64][65];
    const int k0 = blockIdx.y * 64, n0 = blockIdx.x * 64;
    const int c = threadIdx.x & 63, r4 = threadIdx.x >> 6;
#pragma unroll
    for (int i = 0; i < 16; i++) {
        int r = r4 * 16 + i;
        tile[r][c] = Bm[(size_t)(k0 + r) * Hn + n0 + c];
    }
    __syncthreads();
#pragma unroll
    for (int i = 0; i < 16; i++) {
        int r = r4 * 16 + i;
        float v = tile[c][r];                 // Bm[k0+c][n0+r]
        unsigned short x1 = f2bf(v);
        unsigned short x2 = f2bf(v - bf2f(x1));
        b1[(size_t)(n0 + r) * Hn + k0 + c] = x1;
        b2[(size_t)(n0 + r) * Hn + k0 + c] = x2;
    }
}

// ---------------------------------------------------------------------------
// Main split-GEMM template.
// PHASE 1: Out[m,n] = sum_k X[m,k]*Bt[n,k]          (X fp32 inline-split, 3 products)
// PHASE 2: v = (reset?0:acc)+Out; Out=v; splits(v)  (6 products)
// PHASE 4: val = alive?acc:0; Out+=val; splits(val) (6 products, early-out)
// ---------------------------------------------------------------------------
template<int BM, int BN, int SA, int SB, int NP, int PHASE>
__global__ __launch_bounds__(256) void k_gemm(const unsigned short* __restrict__ A0,
                                              const unsigned short* __restrict__ A1,
                                              const unsigned short* __restrict__ A2,
                                              const unsigned short* __restrict__ B0,
                                              const unsigned short* __restrict__ B1,
                                              const unsigned short* __restrict__ B2,
                                              const float* __restrict__ Xf,
                                              float* __restrict__ Out,
                                              unsigned short* __restrict__ O0,
                                              unsigned short* __restrict__ O1,
                                              unsigned short* __restrict__ O2,
                                              const unsigned char* __restrict__ r8v,
                                              const int* __restrict__ fR,
                                              int j) {
    constexpr int FM = BM / 32, FN = BN / 32;   // frags per wave (2x2 wave grid)
    constexpr int LW = 40;                       // padded LDS row (bf16), 80B stride
    __shared__ unsigned short ldsA[SA * BM * LW];
    __shared__ unsigned short ldsB[SB * BN * LW];
    const int tid = threadIdx.x;
    const int lane = tid & 63;
    const int wv = tid >> 6;
    const int wm = wv >> 1, wn = wv & 1;
    const int n0 = blockIdx.x * BN;
    const int m0 = blockIdx.y * BM;

    if constexpr (PHASE == 4) {
        __shared__ int smax;
        if (tid == 0) smax = 0;
        __syncthreads();
        if (tid < BM) atomicMax(&smax, fR[m0 + tid]);
        __syncthreads();
        const int maxFR = smax;
        if (j >= maxFR + 2) return;           // both ping-pong buffers already zero
        if (j >= maxFR) {                     // all rows dead: zero split outputs
            u32x4 z = {0, 0, 0, 0};
            for (int u = tid; u < BM * (BN / 8); u += 256) {
                int row = u / (BN / 8), cq = u % (BN / 8);
                size_t base = (size_t)(m0 + row) * Hn + n0 + cq * 8;
                *(u32x4*)&O0[base] = z;
                *(u32x4*)&O1[base] = z;
                *(u32x4*)&O2[base] = z;
            }
            return;
        }
    }

    f4 acc[FM][FN];
#pragma unroll
    for (int fm = 0; fm < FM; fm++)
#pragma unroll
        for (int fn = 0; fn < FN; fn++) acc[fm][fn] = (f4){0.f, 0.f, 0.f, 0.f};

    const unsigned short* Asp[3] = {A0, A1, A2};
    const unsigned short* Bsp[3] = {B0, B1, B2};
    const int pa[6] = {0, 0, 1, 0, 1, 2};
    const int pb[6] = {0, 1, 0, 2, 1, 0};

    for (int k0 = 0; k0 < Hn; k0 += 32) {
        __syncthreads();
        if constexpr (PHASE == 1) {
            // inline fp32 -> (hi,lo) bf16 split of X
            for (int u = tid; u < BM * 8; u += 256) {
                int row = u >> 3, slot = u & 7;
                f32x4 v = *(const f32x4*)(Xf + (size_t)(m0 + row) * Hn + k0 + slot * 4);
                us4 h1, h2;
#pragma unroll
                for (int e = 0; e < 4; e++) {
                    unsigned short x1 = f2bf(v[e]);
                    h1[e] = x1;
                    h2[e] = f2bf(v[e] - bf2f(x1));
                }
                *(us4*)&ldsA[row * LW + slot * 4] = h1;
                *(us4*)&ldsA[(BM + row) * LW + slot * 4] = h2;
            }
        } else {
#pragma unroll
            for (int sp = 0; sp < SA; sp++) {
                for (int u = tid; u < BM * 4; u += 256) {
                    int row = u >> 2, slot = u & 3;
                    u32x4 v = *(const u32x4*)(Asp[sp] + (size_t)(m0 + row) * Hn + k0 + slot * 8);
                    *(u32x4*)&ldsA[(sp * BM + row) * LW + slot * 8] = v;
                }
            }
        }
#pragma unroll
        for (int sp = 0; sp < SB; sp++) {
            for (int u = tid; u < BN * 4; u += 256) {
                int row = u >> 2, slot = u & 3;
                u32x4 v = *(const u32x4*)(Bsp[sp] + (size_t)(n0 + row) * Hn + k0 + slot * 8);
                *(u32x4*)&ldsB[(sp * BN + row) * LW + slot * 8] = v;
            }
        }
        __syncthreads();

        bf8 af[SA][FM], bfr[SB][FN];
#pragma unroll
        for (int sp = 0; sp < SA; sp++)
#pragma unroll
            for (int f = 0; f < FM; f++)
                af[sp][f] = *(const bf8*)&ldsA[(sp * BM + wm * (FM * 16) + f * 16 + (lane & 15)) * LW + (lane >> 4) * 8];
#pragma unroll
        for (int sp = 0; sp < SB; sp++)
#pragma unroll
            for (int f = 0; f < FN; f++)
                bfr[sp][f] = *(const bf8*)&ldsB[(sp * BN + wn * (FN * 16) + f * 16 + (lane & 15)) * LW + (lane >> 4) * 8];

#pragma unroll
        for (int p = 0; p < NP; p++) {
#pragma unroll
            for (int fm = 0; fm < FM; fm++)
#pragma unroll
                for (int fn = 0; fn < FN; fn++)
                    acc[fm][fn] = __builtin_amdgcn_mfma_f32_16x16x32_bf16(
                        af[pa[p]][fm], bfr[pb[p]][fn], acc[fm][fn], 0, 0, 0);
        }
    }

    // epilogue: D frag mapping row=(lane>>4)*4+r, col=lane&15  [m89/m91]
    if constexpr (PHASE == 1) {
#pragma unroll
        for (int fm = 0; fm < FM; fm++)
#pragma unroll
            for (int r = 0; r < 4; r++) {
                int row = m0 + wm * (FM * 16) + fm * 16 + (lane >> 4) * 4 + r;
                size_t ob = (size_t)row * Hn;
#pragma unroll
                for (int fn = 0; fn < FN; fn++) {
                    int n = n0 + wn * (FN * 16) + fn * 16 + (lane & 15);
                    Out[ob + n] = acc[fm][fn][r];
                }
            }
    } else if constexpr (PHASE == 2) {
#pragma unroll
        for (int fm = 0; fm < FM; fm++)
#pragma unroll
            for (int r = 0; r < 4; r++) {
                int m = m0 + wm * (FM * 16) + fm * 16 + (lane >> 4) * 4 + r;
                int cch = m >> 3, bb = m & 7;
                int t = cch * Cn + j;
                int rfl = r8v[bb * Tn + t];
                size_t ob = ((size_t)bb * Tn + t) * (size_t)Hn;
                size_t sb = (size_t)m * Hn;
#pragma unroll
                for (int fn = 0; fn < FN; fn++) {
                    int n = n0 + wn * (FN * 16) + fn * 16 + (lane & 15);
                    float v = (rfl ? 0.0f : acc[fm][fn][r]) + Out[ob + n];
                    Out[ob + n] = v;
                    unsigned short h1, h2, h3;
                    split3f(v, h1, h2, h3);
                    O0[sb + n] = h1; O1[sb + n] = h2; O2[sb + n] = h3;
                }
            }
    } else {  // PHASE 4
#pragma unroll
        for (int fm = 0; fm < FM; fm++)
#pragma unroll
            for (int r = 0; r < 4; r++) {
                int m = m0 + wm * (FM * 16) + fm * 16 + (lane >> 4) * 4 + r;
                int cch = m >> 3, bb = m & 7;
                int t = cch * Cn + j;
                int alive = (j < fR[m]);
                size_t ob = ((size_t)bb * Tn + t) * (size_t)Hn;
                size_t sb = (size_t)m * Hn;
#pragma unroll
                for (int fn = 0; fn < FN; fn++) {
                    int n = n0 + wn * (FN * 16) + fn * 16 + (lane & 15);
                    float val = alive ? acc[fm][fn][r] : 0.0f;
                    unsigned short h1, h2, h3;
                    split3f(val, h1, h2, h3);
                    O0[sb + n] = h1; O1[sb + n] = h2; O2[sb + n] = h3;
                    if (alive) Out[ob + n] += val;
                }
            }
    }
}

// ---------------------------------------------------------------------------
// Scan step j=0: h = bx (h_prev=0), just split Out slice into state buffers.
// ---------------------------------------------------------------------------
__global__ __launch_bounds__(256) void k_step0(const float* __restrict__ Out,
                                               unsigned short* __restrict__ s1,
                                               unsigned short* __restrict__ s2,
                                               unsigned short* __restrict__ s3) {
    int i = blockIdx.x * 256 + threadIdx.x;
    int m = i >> 9;
    int nq = (i & 511) * 4;
    int c = m >> 3, b = m & 7;
    f32x4 v = *(const f32x4*)&Out[((size_t)b * Tn + c * Cn) * Hn + nq];
    us4 h1, h2, h3;
#pragma unroll
    for (int e = 0; e < 4; e++) {
        unsigned short x1, x2, x3;
        split3f(v[e], x1, x2, x3);
        h1[e] = x1; h2[e] = x2; h3[e] = x3;
    }
    size_t o = (size_t)m * Hn + nq;
    *(us4*)&s1[o] = h1; *(us4*)&s2[o] = h2; *(us4*)&s3[o] = h3;
}

// ---------------------------------------------------------------------------
// Carry-in: Hin[c] = local_end[c-1]; write fp32 (for fallback) + splits.
// ---------------------------------------------------------------------------
__global__ __launch_bounds__(256) void k_hin_split(const float* __restrict__ Out,
                                                   float* __restrict__ Hin,
                                                   unsigned short* __restrict__ u1,
                                                   unsigned short* __restrict__ u2,
                                                   unsigned short* __restrict__ u3) {
    int i = blockIdx.x * 256 + threadIdx.x;
    int m = i >> 9;
    int nq = (i & 511) * 4;
    int c = m >> 3, b = m & 7;
    f32x4 v = {0.f, 0.f, 0.f, 0.f};
    if (c) v = *(const f32x4*)&Out[((size_t)b * Tn + (size_t)c * Cn - 1) * Hn + nq];
    size_t o = (size_t)m * Hn + nq;
    *(f32x4*)&Hin[o] = v;
    us4 h1, h2, h3;
#pragma unroll
    for (int e = 0; e < 4; e++) {
        unsigned short x1, x2, x3;
        split3f(v[e], x1, x2, x3);
        h1[e] = x1; h2[e] = x2; h3[e] = x3;
    }
    *(us4*)&u1[o] = h1; *(us4*)&u2[o] = h2; *(us4*)&u3[o] = h3;
}

// ---------------------------------------------------------------------------
// Exact fallback for uncut chunks (prob ~2^-16 per row-chunk); updates fp32
// Hin and the corresponding split buffers.
// ---------------------------------------------------------------------------
__global__ __launch_bounds__(1024) void k_fallback(float* __restrict__ Hin,
                                                   const float* __restrict__ A,
                                                   const int* __restrict__ cut,
                                                   const int* __restrict__ anyUncut,
                                                   unsigned short* __restrict__ u1,
                                                   unsigned short* __restrict__ u2,
                                                   unsigned short* __restrict__ u3) {
    if (*anyUncut == 0) return;
    __shared__ float v0[Hn];
    __shared__ float v1[Hn];
    for (int c = 1; c < NCn; c++) {
        for (int b = 0; b < Bn; b++) {
            if (cut[(c - 1) * Bn + b]) continue;
            for (int n = threadIdx.x; n < Hn; n += 1024)
                v0[n] = Hin[((size_t)(c - 1) * Bn + b) * Hn + n];
            __syncthreads();
            for (int s = 0; s < Cn; s++) {
                float* pin = (s & 1) ? v1 : v0;
                float* pout = (s & 1) ? v0 : v1;
                for (int n = threadIdx.x; n < Hn; n += 1024) {
                    float accv = 0.0f;
                    const float* Ar = &A[(size_t)n * Hn];
                    for (int k = 0; k < Hn; k++) accv += pin[k] * Ar[k];
                    pout[n] = accv;
                }
                __syncthreads();
            }
            float* pres = (Cn & 1) ? v1 : v0;
            size_t dst = ((size_t)c * Bn + b) * Hn;
            for (int n = threadIdx.x; n < Hn; n += 1024) {
                float nv = Hin[dst + n] + pres[n];
                Hin[dst + n] = nv;
                unsigned short h1, h2, h3;
                split3f(nv, h1, h2, h3);
                u1[dst + n] = h1; u2[dst + n] = h2; u3[dst + n] = h3;
            }
            __syncthreads();
        }
    }
}

extern "C" void kernel_launch(void* const* d_in, const int* in_sizes, int n_in,
                              void* d_out, int out_size, void* d_ws, size_t ws_size,
                              hipStream_t stream) {
    const float* x = (const float*)d_in[0];
    const unsigned int* rst = (const unsigned int*)d_in[1];
    const float* Am = (const float*)d_in[2];
    const float* Bm = (const float*)d_in[3];
    float* Out = (float*)d_out;
    char* ws = (char*)d_ws;

    unsigned char* r8 = (unsigned char*)ws;                 // 16 KB
    int* cut = (int*)(ws + 16384);
    int* firstReset = (int*)(ws + 20480);
    int* anyUncut = (int*)(ws + 24576);
    unsigned short* a1 = (unsigned short*)(ws + 32768);     // 3x 8MB A splits [n][k]
    unsigned short* a2 = a1 + 4194304;
    unsigned short* a3 = a2 + 4194304;
    unsigned short* b1 = a3 + 4194304;                      // 2x 8MB Bt splits [n][k]
    unsigned short* b2 = b1 + 4194304;
    unsigned short* sP1 = b2 + 4194304;                     // state/u splits ping (3x 4MB)
    unsigned short* sP2 = sP1 + 2097152;
    unsigned short* sP3 = sP2 + 2097152;
    unsigned short* sQ1 = sP3 + 2097152;                    // pong (3x 4MB)
    unsigned short* sQ2 = sQ1 + 2097152;
    unsigned short* sQ3 = sQ2 + 2097152;
    float* Hin = (float*)(sQ3 + 2097152);                   // 8MB fp32

    k_reset_prep<<<1, 256, 0, stream>>>(rst, r8, cut, firstReset, anyUncut);
    k_split_A3<<<4096, 256, 0, stream>>>(Am, a1, a2, a3);
    k_split_Bt<<<dim3(32, 32), 256, 0, stream>>>(Bm, b1, b2);

    // Phase 1: bx = x @ B  (2-way splits, 3 products)
    k_gemm<128, 128, 2, 2, 3, 1><<<dim3(Hn / 128, (Bn * Tn) / 128), 256, 0, stream>>>(
        nullptr, nullptr, nullptr, b1, b2, nullptr, x, Out,
        nullptr, nullptr, nullptr, nullptr, nullptr, 0);

    // Phase 2: chunk-local scans
    k_step0<<<2048, 256, 0, stream>>>(Out, sP1, sP2, sP3);
    for (int j = 1; j < Cn; j++) {
        const unsigned short* i1 = (j & 1) ? sP1 : sQ1;
        const unsigned short* i2 = (j & 1) ? sP2 : sQ2;
        const unsigned short* i3 = (j & 1) ? sP3 : sQ3;
        unsigned short* o1 = (j & 1) ? sQ1 : sP1;
        unsigned short* o2 = (j & 1) ? sQ2 : sP2;
        unsigned short* o3 = (j & 1) ? sQ3 : sP3;
        k_gemm<64, 128, 3, 3, 6, 2><<<dim3(Hn / 128, M2n / 64), 256, 0, stream>>>(
            i1, i2, i3, a1, a2, a3, nullptr, Out, o1, o2, o3, r8, nullptr, j);
    }

    // Phase 3: carry-in + exact fallback
    k_hin_split<<<2048, 256, 0, stream>>>(Out, Hin, sP1, sP2, sP3);
    k_fallback<<<1, 1024, 0, stream>>>(Hin, Am, cut, anyUncut, sP1, sP2, sP3);

    // Phase 4: corrections
    for (int j = 0; j < Cn; j++) {
        const unsigned short* i1 = (j & 1) ? sQ1 : sP1;
        const unsigned short* i2 = (j & 1) ? sQ2 : sP2;
        const unsigned short* i3 = (j & 1) ? sQ3 : sP3;
        unsigned short* o1 = (j & 1) ? sP1 : sQ1;
        unsigned short* o2 = (j & 1) ? sP2 : sQ2;
        unsigned short* o3 = (j & 1) ? sP3 : sQ3;
        k_gemm<64, 128, 3, 3, 6, 4><<<dim3(Hn / 128, M2n / 64), 256, 0, stream>>>(
            i1, i2, i3, a1, a2, a3, nullptr, Out, o1, o2, o3, r8, firstReset, j);
    }
}

// Round 3
// 1831.921 us; speedup vs baseline: 6.2432x; 2.5235x over previous
//
#include <hip/hip_runtime.h>

#define Hn 2048
#define Bn 8
#define Tn 2048
#define Cn 16
#define NCn (Tn / Cn)     // 128 chunks
#define M2n (NCn * Bn)    // 1024 scan rows

using f32x4 = __attribute__((ext_vector_type(4))) float;
using u32x4 = __attribute__((ext_vector_type(4))) unsigned int;
using us4   = __attribute__((ext_vector_type(4))) unsigned short;
using bf8   = __attribute__((ext_vector_type(8))) short;
using f4    = __attribute__((ext_vector_type(4))) float;

__device__ __forceinline__ unsigned short f2bf(float f) {
    unsigned u = __builtin_bit_cast(unsigned, f);
    u = u + 0x7fffu + ((u >> 16) & 1u);
    return (unsigned short)(u >> 16);
}
__device__ __forceinline__ float bf2f(unsigned short h) {
    unsigned u = ((unsigned)h) << 16;
    return __builtin_bit_cast(float, u);
}
__device__ __forceinline__ void split2f(float v, unsigned short& a, unsigned short& b) {
    a = f2bf(v);
    b = f2bf(v - bf2f(a));
}

// ---------------------------------------------------------------------------
// K0: canonicalize reset, firstReset/cut/anyUncut, counting-sort rows by
//     firstReset DESC -> perm/iperm/counts (alive prefix per correction step).
// ---------------------------------------------------------------------------
__global__ __launch_bounds__(256) void k_reset_prep(const unsigned int* __restrict__ rin,
                                                    unsigned char* __restrict__ r8,
                                                    int* __restrict__ cut,
                                                    int* __restrict__ firstReset,
                                                    int* __restrict__ anyUncut,
                                                    int* __restrict__ perm,
                                                    int* __restrict__ iperm,
                                                    int* __restrict__ counts) {
    __shared__ int s_badInt, s_badFloat;
    __shared__ int hist[17], off[18], cur[17];
    if (threadIdx.x == 0) { s_badInt = 0; s_badFloat = 0; *anyUncut = 0; }
    if (threadIdx.x < 17) hist[threadIdx.x] = 0;
    __syncthreads();
    int badI = 0, badF = 0;
    for (int i = threadIdx.x; i < 4096; i += 256) {
        unsigned int v = rin[i];
        if (v > 1u) badI = 1;
        if (v != 0u && v != 0x3f800000u) badF = 1;
    }
    if (badI) atomicOr(&s_badInt, 1);
    if (badF) atomicOr(&s_badFloat, 1);
    __syncthreads();
    const int fmt = (!s_badInt) ? 0 : ((!s_badFloat) ? 1 : 2);
    const unsigned char* rb = (const unsigned char*)rin;
    const float* rf = (const float*)rin;
    for (int i = threadIdx.x; i < Bn * Tn; i += 256) {
        unsigned char v;
        if (fmt == 0)      v = (unsigned char)(rin[i] != 0u);
        else if (fmt == 1) v = (unsigned char)(rf[i] != 0.0f);
        else               v = (unsigned char)(rb[i] != 0);
        r8[i] = v;
    }
    __syncthreads();
    int anyU = 0;
    for (int m = threadIdx.x; m < M2n; m += 256) {
        int c = m / Bn, b = m % Bn;
        int fr = Cn;
        for (int j = 0; j < Cn; j++) {
            if (r8[b * Tn + c * Cn + j]) { fr = j; break; }
        }
        firstReset[m] = fr;
        int ct = (fr < Cn);
        cut[m] = ct;
        if (!ct && c < NCn - 1) anyU = 1;
        atomicAdd(&hist[fr], 1);
    }
    if (anyU) atomicOr(anyUncut, 1);
    __syncthreads();
    if (threadIdx.x == 0) {
        off[16] = 0;
        for (int v = 15; v >= 0; v--) off[v] = off[v + 1] + hist[v + 1];
        for (int v = 0; v < 17; v++) cur[v] = (v == 16) ? 0 : off[v];
        for (int j = 0; j < 16; j++) counts[j] = off[j];
    }
    __syncthreads();
    for (int m = threadIdx.x; m < M2n; m += 256) {
        int fr = firstReset[m];
        int pos = atomicAdd(&cur[fr], 1);
        perm[pos] = m;
        iperm[m] = pos;
    }
}

// ---------------------------------------------------------------------------
// Split pre-passes (2-way hi/lo)
// ---------------------------------------------------------------------------
__global__ __launch_bounds__(256) void k_split_A2(const float* __restrict__ A,
                                                  unsigned short* __restrict__ a1,
                                                  unsigned short* __restrict__ a2) {
    size_t i = ((size_t)blockIdx.x * 256 + threadIdx.x) * 4;
    f32x4 v = *(const f32x4*)&A[i];
    us4 h1, h2;
#pragma unroll
    for (int e = 0; e < 4; e++) {
        unsigned short x1, x2;
        split2f(v[e], x1, x2);
        h1[e] = x1; h2[e] = x2;
    }
    *(us4*)&a1[i] = h1; *(us4*)&a2[i] = h2;
}

__global__ __launch_bounds__(256) void k_split_Bt(const float* __restrict__ Bm,
                                                  unsigned short* __restrict__ b1,
                                                  unsigned short* __restrict__ b2) {
    __shared__ float tile[64][65];
    const int k0 = blockIdx.y * 64, n0 = blockIdx.x * 64;
    const int c = threadIdx.x & 63, r4 = threadIdx.x >> 6;
#pragma unroll
    for (int i = 0; i < 16; i++) {
        int r = r4 * 16 + i;
        tile[r][c] = Bm[(size_t)(k0 + r) * Hn + n0 + c];
    }
    __syncthreads();
#pragma unroll
    for (int i = 0; i < 16; i++) {
        int r = r4 * 16 + i;
        float v = tile[c][r];                 // Bm[k0+c][n0+r]
        unsigned short x1, x2;
        split2f(v, x1, x2);
        b1[(size_t)(n0 + r) * Hn + k0 + c] = x1;
        b2[(size_t)(n0 + r) * Hn + k0 + c] = x2;
    }
}

__global__ __launch_bounds__(256) void k_split_X(const float* __restrict__ X,
                                                 unsigned short* __restrict__ x1,
                                                 unsigned short* __restrict__ x2) {
    size_t i = ((size_t)blockIdx.x * 256 + threadIdx.x) * 4;
    f32x4 v = *(const f32x4*)&X[i];
    us4 h1, h2;
#pragma unroll
    for (int e = 0; e < 4; e++) {
        unsigned short a, b;
        split2f(v[e], a, b);
        h1[e] = a; h2[e] = b;
    }
    *(us4*)&x1[i] = h1; *(us4*)&x2[i] = h2;
}

// ---------------------------------------------------------------------------
// Split-GEMM template, 3 products (hi*hi + hi*lo + lo*hi).
// PHASE 1: bx GEMM, X split inline (ws-too-small fallback), plain store.
// PHASE 5: bx GEMM from pre-split X, plain store.
// PHASE 2: scan step: v=(reset?0:acc)+Out; Out=v; split2 -> state.
// PHASE 4: correction on sorted alive prefix; scatter-add via perm.
// ---------------------------------------------------------------------------
template<int BM, int BN, int PHASE>
__global__ __launch_bounds__(256) void k_gemm(const unsigned short* __restrict__ A0,
                                              const unsigned short* __restrict__ A1,
                                              const unsigned short* __restrict__ B0,
                                              const unsigned short* __restrict__ B1,
                                              const float* __restrict__ Xf,
                                              float* __restrict__ Out,
                                              unsigned short* __restrict__ O0,
                                              unsigned short* __restrict__ O1,
                                              const unsigned char* __restrict__ r8v,
                                              const int* __restrict__ perm,
                                              const int* __restrict__ counts,
                                              int j) {
    constexpr int FM = BM / 32, FN = BN / 32;   // 2x2 wave grid
    constexpr int LW = 40;                       // padded LDS row (bf16), 80B stride
    __shared__ unsigned short ldsA[2 * BM * LW];
    __shared__ unsigned short ldsB[2 * BN * LW];
    const int tid = threadIdx.x;
    const int lane = tid & 63;
    const int wv = tid >> 6;
    const int wm = wv >> 1, wn = wv & 1;
    const int n0 = blockIdx.x * BN;
    const int m0 = blockIdx.y * BM;

    int cnt = 0;
    if constexpr (PHASE == 4) {
        cnt = counts[j];
        if (m0 >= cnt) return;
    }

    f4 acc[FM][FN];
#pragma unroll
    for (int fm = 0; fm < FM; fm++)
#pragma unroll
        for (int fn = 0; fn < FN; fn++) acc[fm][fn] = (f4){0.f, 0.f, 0.f, 0.f};

    const unsigned short* Asp[2] = {A0, A1};
    const unsigned short* Bsp[2] = {B0, B1};
    const int pa[3] = {0, 0, 1};
    const int pb[3] = {0, 1, 0};

    for (int k0 = 0; k0 < Hn; k0 += 32) {
        __syncthreads();
        if constexpr (PHASE == 1) {
            for (int u = tid; u < BM * 8; u += 256) {
                int row = u >> 3, slot = u & 7;
                f32x4 v = *(const f32x4*)(Xf + (size_t)(m0 + row) * Hn + k0 + slot * 4);
                us4 h1, h2;
#pragma unroll
                for (int e = 0; e < 4; e++) {
                    unsigned short x1, x2;
                    split2f(v[e], x1, x2);
                    h1[e] = x1; h2[e] = x2;
                }
                *(us4*)&ldsA[row * LW + slot * 4] = h1;
                *(us4*)&ldsA[(BM + row) * LW + slot * 4] = h2;
            }
        } else {
#pragma unroll
            for (int sp = 0; sp < 2; sp++) {
                for (int u = tid; u < BM * 4; u += 256) {
                    int row = u >> 2, slot = u & 3;
                    u32x4 v = *(const u32x4*)(Asp[sp] + (size_t)(m0 + row) * Hn + k0 + slot * 8);
                    *(u32x4*)&ldsA[(sp * BM + row) * LW + slot * 8] = v;
                }
            }
        }
#pragma unroll
        for (int sp = 0; sp < 2; sp++) {
            for (int u = tid; u < BN * 4; u += 256) {
                int row = u >> 2, slot = u & 3;
                u32x4 v = *(const u32x4*)(Bsp[sp] + (size_t)(n0 + row) * Hn + k0 + slot * 8);
                *(u32x4*)&ldsB[(sp * BN + row) * LW + slot * 8] = v;
            }
        }
        __syncthreads();

        bf8 af[2][FM], bfr[2][FN];
#pragma unroll
        for (int sp = 0; sp < 2; sp++)
#pragma unroll
            for (int f = 0; f < FM; f++)
                af[sp][f] = *(const bf8*)&ldsA[(sp * BM + wm * (FM * 16) + f * 16 + (lane & 15)) * LW + (lane >> 4) * 8];
#pragma unroll
        for (int sp = 0; sp < 2; sp++)
#pragma unroll
            for (int f = 0; f < FN; f++)
                bfr[sp][f] = *(const bf8*)&ldsB[(sp * BN + wn * (FN * 16) + f * 16 + (lane & 15)) * LW + (lane >> 4) * 8];

#pragma unroll
        for (int p = 0; p < 3; p++) {
#pragma unroll
            for (int fm = 0; fm < FM; fm++)
#pragma unroll
                for (int fn = 0; fn < FN; fn++)
                    acc[fm][fn] = __builtin_amdgcn_mfma_f32_16x16x32_bf16(
                        af[pa[p]][fm], bfr[pb[p]][fn], acc[fm][fn], 0, 0, 0);
        }
    }

    // D frag mapping: row=(lane>>4)*4+r, col=lane&15  [m89/m91]
    if constexpr (PHASE == 1 || PHASE == 5) {
#pragma unroll
        for (int fm = 0; fm < FM; fm++)
#pragma unroll
            for (int r = 0; r < 4; r++) {
                int row = m0 + wm * (FM * 16) + fm * 16 + (lane >> 4) * 4 + r;
                size_t ob = (size_t)row * Hn;
#pragma unroll
                for (int fn = 0; fn < FN; fn++) {
                    int n = n0 + wn * (FN * 16) + fn * 16 + (lane & 15);
                    Out[ob + n] = acc[fm][fn][r];
                }
            }
    } else if constexpr (PHASE == 2) {
#pragma unroll
        for (int fm = 0; fm < FM; fm++)
#pragma unroll
            for (int r = 0; r < 4; r++) {
                int m = m0 + wm * (FM * 16) + fm * 16 + (lane >> 4) * 4 + r;
                int cch = m >> 3, bb = m & 7;
                int t = cch * Cn + j;
                int rfl = r8v[bb * Tn + t];
                size_t ob = ((size_t)bb * Tn + t) * (size_t)Hn;
                size_t sb = (size_t)m * Hn;
#pragma unroll
                for (int fn = 0; fn < FN; fn++) {
                    int n = n0 + wn * (FN * 16) + fn * 16 + (lane & 15);
                    float v = (rfl ? 0.0f : acc[fm][fn][r]) + Out[ob + n];
                    Out[ob + n] = v;
                    unsigned short h1, h2;
                    split2f(v, h1, h2);
                    O0[sb + n] = h1; O1[sb + n] = h2;
                }
            }
    } else {  // PHASE 4 (sorted prefix)
#pragma unroll
        for (int fm = 0; fm < FM; fm++)
#pragma unroll
            for (int r = 0; r < 4; r++) {
                int s = m0 + wm * (FM * 16) + fm * 16 + (lane >> 4) * 4 + r;
                int alive = (s < cnt);
                int m = perm[s];
                int cch = m >> 3, bb = m & 7;
                int t = cch * Cn + j;
                size_t ob = ((size_t)bb * Tn + t) * (size_t)Hn;
                size_t sb = (size_t)s * Hn;
#pragma unroll
                for (int fn = 0; fn < FN; fn++) {
                    int n = n0 + wn * (FN * 16) + fn * 16 + (lane & 15);
                    if (alive) {
                        float val = acc[fm][fn][r];
                        unsigned short h1, h2;
                        split2f(val, h1, h2);
                        O0[sb + n] = h1; O1[sb + n] = h2;
                        Out[ob + n] += val;
                    }
                }
            }
    }
}

// ---------------------------------------------------------------------------
// Scan step j=0: state = bx slice, split2.
// ---------------------------------------------------------------------------
__global__ __launch_bounds__(256) void k_step0(const float* __restrict__ Out,
                                               unsigned short* __restrict__ s1,
                                               unsigned short* __restrict__ s2) {
    int i = blockIdx.x * 256 + threadIdx.x;
    int m = i >> 9;
    int nq = (i & 511) * 4;
    int c = m >> 3, b = m & 7;
    f32x4 v = *(const f32x4*)&Out[((size_t)b * Tn + c * Cn) * Hn + nq];
    us4 h1, h2;
#pragma unroll
    for (int e = 0; e < 4; e++) {
        unsigned short x1, x2;
        split2f(v[e], x1, x2);
        h1[e] = x1; h2[e] = x2;
    }
    size_t o = (size_t)m * Hn + nq;
    *(us4*)&s1[o] = h1; *(us4*)&s2[o] = h2;
}

// ---------------------------------------------------------------------------
// Carry-in: sorted u_0 splits + fp32 Hin (orig order, for fallback).
// ---------------------------------------------------------------------------
__global__ __launch_bounds__(256) void k_hin_split(const float* __restrict__ Out,
                                                   float* __restrict__ Hin,
                                                   unsigned short* __restrict__ u1,
                                                   unsigned short* __restrict__ u2,
                                                   const int* __restrict__ perm) {
    int i = blockIdx.x * 256 + threadIdx.x;
    int s = i >> 9;
    int nq = (i & 511) * 4;
    int m = perm[s];
    int c = m >> 3, b = m & 7;
    f32x4 v = {0.f, 0.f, 0.f, 0.f};
    if (c) v = *(const f32x4*)&Out[((size_t)b * Tn + (size_t)c * Cn - 1) * Hn + nq];
    *(f32x4*)&Hin[(size_t)m * Hn + nq] = v;
    us4 h1, h2;
#pragma unroll
    for (int e = 0; e < 4; e++) {
        unsigned short x1, x2;
        split2f(v[e], x1, x2);
        h1[e] = x1; h2[e] = x2;
    }
    size_t o = (size_t)s * Hn + nq;
    *(us4*)&u1[o] = h1; *(us4*)&u2[o] = h2;
}

// ---------------------------------------------------------------------------
// Exact fallback for uncut chunks (E[occurrences] ~ 0.016).
// ---------------------------------------------------------------------------
__global__ __launch_bounds__(1024) void k_fallback(float* __restrict__ Hin,
                                                   const float* __restrict__ A,
                                                   const int* __restrict__ cut,
                                                   const int* __restrict__ anyUncut,
                                                   unsigned short* __restrict__ u1,
                                                   unsigned short* __restrict__ u2,
                                                   const int* __restrict__ iperm) {
    if (*anyUncut == 0) return;
    __shared__ float v0[Hn];
    __shared__ float v1[Hn];
    for (int c = 1; c < NCn; c++) {
        for (int b = 0; b < Bn; b++) {
            if (cut[(c - 1) * Bn + b]) continue;
            for (int n = threadIdx.x; n < Hn; n += 1024)
                v0[n] = Hin[((size_t)(c - 1) * Bn + b) * Hn + n];
            __syncthreads();
            for (int s = 0; s < Cn; s++) {
                float* pin = (s & 1) ? v1 : v0;
                float* pout = (s & 1) ? v0 : v1;
                for (int n = threadIdx.x; n < Hn; n += 1024) {
                    float accv = 0.0f;
                    const float* Ar = &A[(size_t)n * Hn];
                    for (int k = 0; k < Hn; k++) accv += pin[k] * Ar[k];
                    pout[n] = accv;
                }
                __syncthreads();
            }
            float* pres = (Cn & 1) ? v1 : v0;
            int mrow = c * Bn + b;
            size_t dst = (size_t)mrow * Hn;
            size_t sdst = (size_t)iperm[mrow] * Hn;
            for (int n = threadIdx.x; n < Hn; n += 1024) {
                float nv = Hin[dst + n] + pres[n];
                Hin[dst + n] = nv;
                unsigned short h1, h2;
                split2f(nv, h1, h2);
                u1[sdst + n] = h1; u2[sdst + n] = h2;
            }
            __syncthreads();
        }
    }
}

extern "C" void kernel_launch(void* const* d_in, const int* in_sizes, int n_in,
                              void* d_out, int out_size, void* d_ws, size_t ws_size,
                              hipStream_t stream) {
    const float* x = (const float*)d_in[0];
    const unsigned int* rst = (const unsigned int*)d_in[1];
    const float* Am = (const float*)d_in[2];
    const float* Bm = (const float*)d_in[3];
    float* Out = (float*)d_out;
    char* ws = (char*)d_ws;

    unsigned char* r8 = (unsigned char*)ws;                 // 16 KB
    int* cut = (int*)(ws + 16384);
    int* firstReset = (int*)(ws + 20480);
    int* perm = (int*)(ws + 24576);
    int* iperm = (int*)(ws + 28672);
    int* counts = (int*)(ws + 32768);
    int* anyUncut = (int*)(ws + 32832);
    unsigned short* a1 = (unsigned short*)(ws + 65536);     // A splits [n][k], 8MB ea
    unsigned short* a2 = a1 + 4194304;
    unsigned short* b1 = a2 + 4194304;                      // Bt splits [n][k], 8MB ea
    unsigned short* b2 = b1 + 4194304;
    unsigned short* sP1 = b2 + 4194304;                     // state/u splits, 4MB ea
    unsigned short* sP2 = sP1 + 2097152;
    unsigned short* sQ1 = sP2 + 2097152;
    unsigned short* sQ2 = sQ1 + 2097152;
    float* Hin = (float*)(sQ2 + 2097152);                   // 8MB fp32
    unsigned short* x1 = (unsigned short*)(Hin + 2097152);  // X splits, 67MB ea
    unsigned short* x2 = x1 + 33554432;
    const size_t NEED_X = 193003520ull;
    const bool prex = (ws_size >= NEED_X);

    k_reset_prep<<<1, 256, 0, stream>>>(rst, r8, cut, firstReset, anyUncut, perm, iperm, counts);
    k_split_A2<<<4096, 256, 0, stream>>>(Am, a1, a2);
    k_split_Bt<<<dim3(32, 32), 256, 0, stream>>>(Bm, b1, b2);

    // Phase 1: bx = x @ B
    if (prex) {
        k_split_X<<<32768, 256, 0, stream>>>(x, x1, x2);
        k_gemm<128, 128, 5><<<dim3(Hn / 128, (Bn * Tn) / 128), 256, 0, stream>>>(
            x1, x2, b1, b2, nullptr, Out, nullptr, nullptr, nullptr, nullptr, nullptr, 0);
    } else {
        k_gemm<128, 128, 1><<<dim3(Hn / 128, (Bn * Tn) / 128), 256, 0, stream>>>(
            nullptr, nullptr, b1, b2, x, Out, nullptr, nullptr, nullptr, nullptr, nullptr, 0);
    }

    // Phase 2: chunk-local scans
    k_step0<<<2048, 256, 0, stream>>>(Out, sP1, sP2);
    for (int j = 1; j < Cn; j++) {
        const unsigned short* i1 = (j & 1) ? sP1 : sQ1;
        const unsigned short* i2 = (j & 1) ? sP2 : sQ2;
        unsigned short* o1 = (j & 1) ? sQ1 : sP1;
        unsigned short* o2 = (j & 1) ? sQ2 : sP2;
        k_gemm<64, 64, 2><<<dim3(Hn / 64, M2n / 64), 256, 0, stream>>>(
            i1, i2, a1, a2, nullptr, Out, o1, o2, r8, nullptr, nullptr, j);
    }

    // Phase 3: carry-in (sorted) + exact fallback
    k_hin_split<<<2048, 256, 0, stream>>>(Out, Hin, sP1, sP2, perm);
    k_fallback<<<1, 1024, 0, stream>>>(Hin, Am, cut, anyUncut, sP1, sP2, iperm);

    // Phase 4: corrections on shrinking sorted prefix
    for (int j = 0; j < Cn; j++) {
        const unsigned short* i1 = (j & 1) ? sQ1 : sP1;
        const unsigned short* i2 = (j & 1) ? sQ2 : sP2;
        unsigned short* o1 = (j & 1) ? sP1 : sQ1;
        unsigned short* o2 = (j & 1) ? sP2 : sQ2;
        k_gemm<64, 64, 4><<<dim3(Hn / 64, M2n / 64), 256, 0, stream>>>(
            i1, i2, a1, a2, nullptr, Out, o1, o2, nullptr, perm, counts, j);
    }
}